// Round 1
// baseline (12372.836 us; speedup 1.0000x reference)
//
#include <hip/hip_runtime.h>
#include <hip/hip_bf16.h>

// ---------------------------------------------------------------------------
// Longformer forward, MI355X. Round 0: correctness-first.
//   GEMMs: bf16 MFMA 128x128 tile (fp32 accum). Attention: fp32 VALU flash.
// Constants: B=1 NW=8 SEG=511 S=4096 W=256 C=16 H=12 D=64 DM=768 FF=3072 L=12
// ---------------------------------------------------------------------------

typedef unsigned short u16;
typedef __attribute__((ext_vector_type(4))) float floatx4;
typedef __attribute__((ext_vector_type(4))) unsigned int uintx4;
typedef __attribute__((ext_vector_type(8))) short bf16x8;

#define S_LEN 4096
#define DM 768
#define NH 12
#define HD 64
#define FF 3072
#define NL 12
#define QKVG_N 3840   // q(768) k(768) v(768) kg(768) vg(768)

__device__ inline u16 f2bf(float x) {
    union { __hip_bfloat16 b; u16 u; } cv;
    cv.b = __float2bfloat16(x);
    return cv.u;
}

__device__ inline float gelu_f(float x) {
    float x3 = x * x * x;
    return 0.5f * x * (1.0f + tanhf(0.7978845608028654f * (x + 0.044715f * x3)));
}

// ---------------------------------------------------------------------------
// Weight prep: fp32 [K][N] -> bf16 [N][K] (transposed) + bias concat.
// Segments: Wq,Wk,Wv,Wkg,Wvg -> wqkvgT rows 0..3839 ; Wo -> woT ; W1 -> w1T ;
// W2 -> w2T.  Tiles 32x32. 8064 transpose blocks + 15 bias blocks.
// ---------------------------------------------------------------------------
__global__ __launch_bounds__(256) void prep_weights_k(
    const float* __restrict__ Wq, const float* __restrict__ Wk, const float* __restrict__ Wv,
    const float* __restrict__ Wkg, const float* __restrict__ Wvg, const float* __restrict__ Wo,
    const float* __restrict__ W1, const float* __restrict__ W2,
    const float* __restrict__ bq, const float* __restrict__ bk, const float* __restrict__ bv,
    const float* __restrict__ bkg, const float* __restrict__ bvg,
    u16* __restrict__ wqkvgT, u16* __restrict__ woT, u16* __restrict__ w1T,
    u16* __restrict__ w2T, float* __restrict__ bcat)
{
    int bid = blockIdx.x;
    int t = threadIdx.x;
    if (bid >= 8064) {                       // bias concat tail: 3840 floats
        int i = (bid - 8064) * 256 + t;
        float v;
        if (i < 768)       v = bq[i];
        else if (i < 1536) v = bk[i - 768];
        else if (i < 2304) v = bv[i - 1536];
        else if (i < 3072) v = bkg[i - 2304];
        else               v = bvg[i - 3072];
        bcat[i] = v;
        return;
    }
    const float* src; u16* dst; int K, N, tile;
    if (bid < 2880) {
        int m = bid / 576; tile = bid % 576;
        src = (m == 0) ? Wq : (m == 1) ? Wk : (m == 2) ? Wv : (m == 3) ? Wkg : Wvg;
        dst = wqkvgT + (size_t)m * 589824;   // 768*768
        K = 768; N = 768;
    } else if (bid < 3456) { tile = bid - 2880; src = Wo; dst = woT; K = 768; N = 768; }
    else if (bid < 5760)   { tile = bid - 3456; src = W1; dst = w1T; K = 768; N = 3072; }
    else                   { tile = bid - 5760; src = W2; dst = w2T; K = 3072; N = 768; }

    int nt = N >> 5;
    int k0 = (tile / nt) << 5, n0 = (tile % nt) << 5;
    __shared__ float tb[32][33];
    int tx = t & 31, ty = t >> 5;            // ty: 0..7
    #pragma unroll
    for (int r = 0; r < 4; r++)
        tb[ty + r * 8][tx] = src[(size_t)(k0 + ty + r * 8) * N + n0 + tx];
    __syncthreads();
    #pragma unroll
    for (int r = 0; r < 4; r++) {
        int nn = ty + r * 8;
        dst[(size_t)(n0 + nn) * K + k0 + tx] = f2bf(tb[tx][nn]);
    }
}

// ---------------------------------------------------------------------------
// bf16 MFMA GEMM: C[M][N] = A[M][K] @ W[K][N] + bias, W given as W^T [N][K].
// 128x128 block tile, BK=32, 4 waves each 64x64 (4x4 mfma_f32_16x16x32_bf16).
// ACT: 0 none, 1 gelu.  WF: write fp32 Cf.  WB: write bf16 Cb.
// ---------------------------------------------------------------------------
template <int ACT, int WF, int WB>
__global__ __launch_bounds__(256) void gemm_k(
    const u16* __restrict__ A, const u16* __restrict__ Bt,
    const float* __restrict__ bias,
    float* __restrict__ Cf, u16* __restrict__ Cb,
    int N, int K)
{
    __shared__ u16 As[128][32];
    __shared__ u16 Bs[128][32];
    int bm = blockIdx.x * 128, bn = blockIdx.y * 128;
    int t = threadIdx.x, lane = t & 63, wv = t >> 6;
    int wm = (wv >> 1) * 64, wn = (wv & 1) * 64;
    int arow = t >> 2, acol = (t & 3) * 8;     // staging: 64 rows x (4x8 bf16)
    int fr = lane & 15, fo = (lane >> 4) * 8;  // fragment row / k-offset

    floatx4 acc[4][4];
    #pragma unroll
    for (int i = 0; i < 4; i++)
        #pragma unroll
        for (int j = 0; j < 4; j++) acc[i][j] = (floatx4){0.f, 0.f, 0.f, 0.f};

    const int nk = K >> 5;
    for (int kt = 0; kt < nk; ++kt) {
        const u16* ag = A  + (size_t)(bm + arow) * K + kt * 32 + acol;
        const u16* bg = Bt + (size_t)(bn + arow) * K + kt * 32 + acol;
        *(uintx4*)&As[arow][acol]      = *(const uintx4*)ag;
        *(uintx4*)&As[arow + 64][acol] = *(const uintx4*)(ag + (size_t)64 * K);
        *(uintx4*)&Bs[arow][acol]      = *(const uintx4*)bg;
        *(uintx4*)&Bs[arow + 64][acol] = *(const uintx4*)(bg + (size_t)64 * K);
        __syncthreads();
        bf16x8 af[4], bfr[4];
        #pragma unroll
        for (int i = 0; i < 4; i++) af[i]  = *(const bf16x8*)&As[wm + i * 16 + fr][fo];
        #pragma unroll
        for (int i = 0; i < 4; i++) bfr[i] = *(const bf16x8*)&Bs[wn + i * 16 + fr][fo];
        #pragma unroll
        for (int i = 0; i < 4; i++)
            #pragma unroll
            for (int j = 0; j < 4; j++)
                acc[i][j] = __builtin_amdgcn_mfma_f32_16x16x32_bf16(af[i], bfr[j], acc[i][j], 0, 0, 0);
        __syncthreads();
    }

    int dr = (lane >> 4) * 4, dc = lane & 15;
    #pragma unroll
    for (int i = 0; i < 4; i++) {
        #pragma unroll
        for (int j = 0; j < 4; j++) {
            int r0 = bm + wm + i * 16 + dr;
            int cc = bn + wn + j * 16 + dc;
            float bsv = bias[cc];
            #pragma unroll
            for (int r = 0; r < 4; r++) {
                float v = acc[i][j][r] + bsv;
                if (ACT == 1) v = gelu_f(v);
                if (WF) Cf[(size_t)(r0 + r) * N + cc] = v;
                if (WB) Cb[(size_t)(r0 + r) * N + cc] = f2bf(v);
            }
        }
    }
}

// ---------------------------------------------------------------------------
// Embedding + LayerNorm.  ids: per 512-window, pos 0 -> CLS(0), else x token.
// ---------------------------------------------------------------------------
#define BLOCK_MEANVAR(sum, sq, mean, inv)                                        \
    {                                                                            \
        for (int o_ = 32; o_ > 0; o_ >>= 1) {                                    \
            sum += __shfl_down(sum, o_); sq += __shfl_down(sq, o_);              \
        }                                                                        \
        __shared__ float rs_[4], rq_[4];                                         \
        if ((threadIdx.x & 63) == 0) { rs_[threadIdx.x >> 6] = sum; rq_[threadIdx.x >> 6] = sq; } \
        __syncthreads();                                                         \
        float S_ = rs_[0] + rs_[1] + rs_[2] + rs_[3];                            \
        float Q_ = rq_[0] + rq_[1] + rq_[2] + rq_[3];                            \
        mean = S_ * (1.f / 768.f);                                               \
        float var_ = Q_ * (1.f / 768.f) - mean * mean;                           \
        inv = rsqrtf(var_ + 1e-5f);                                              \
    }

__global__ __launch_bounds__(256) void embed_ln_k(
    const int* __restrict__ x, const float* __restrict__ wemb, const float* __restrict__ pemb,
    const float* __restrict__ gs, const float* __restrict__ gb,
    float* __restrict__ hf, u16* __restrict__ hb)
{
    int s = blockIdx.x, t = threadIdx.x;
    int w = s >> 9, p = s & 511;
    int id = (p == 0) ? 0 : x[w * 511 + p - 1];
    float v[3], sum = 0.f, sq = 0.f;
    #pragma unroll
    for (int r = 0; r < 3; r++) {
        int d = t + r * 256;
        float e = wemb[(size_t)id * 768 + d] + pemb[(size_t)s * 768 + d];
        v[r] = e; sum += e; sq += e * e;
    }
    float mean, inv;
    BLOCK_MEANVAR(sum, sq, mean, inv)
    #pragma unroll
    for (int r = 0; r < 3; r++) {
        int d = t + r * 256;
        float y = (v[r] - mean) * inv * gs[d] + gb[d];
        hf[(size_t)s * 768 + d] = y;
        hb[(size_t)s * 768 + d] = f2bf(y);
    }
}

// h = LN(xa + xb); writes fp32 + bf16 (in-place on xa is safe: row-local).
__global__ __launch_bounds__(256) void ln_resid_k(
    const float* __restrict__ xa, const float* __restrict__ xb,
    const float* __restrict__ gs, const float* __restrict__ gb,
    float* __restrict__ of, u16* __restrict__ ob)
{
    int s = blockIdx.x, t = threadIdx.x;
    const float* pa = xa + (size_t)s * 768;
    const float* pb = xb + (size_t)s * 768;
    float v[3], sum = 0.f, sq = 0.f;
    #pragma unroll
    for (int r = 0; r < 3; r++) {
        int d = t + r * 256;
        float e = pa[d] + pb[d];
        v[r] = e; sum += e; sq += e * e;
    }
    float mean, inv;
    BLOCK_MEANVAR(sum, sq, mean, inv)
    #pragma unroll
    for (int r = 0; r < 3; r++) {
        int d = t + r * 256;
        float y = (v[r] - mean) * inv * gs[d] + gb[d];
        of[(size_t)s * 768 + d] = y;
        ob[(size_t)s * 768 + d] = f2bf(y);
    }
}

// ---------------------------------------------------------------------------
// Local banded attention + joint softmax with 8 global CLS keys.
// Block = (head, chunk of 256 queries). Thread = one query. fp32, online
// softmax with deferred max-rescale. qkvg layout: [S][3840] (q,k,v,kg,vg).
// Band: key window index j in [i, i+512]; kpos = c*256-256+j must be in [0,S).
// Writes bf16 attention output [S][768] (head-major cols).
// ---------------------------------------------------------------------------
__global__ __launch_bounds__(256) void attn_local_k(
    const float* __restrict__ qkvg, u16* __restrict__ aob)
{
    int hh = blockIdx.x, c = blockIdx.y;
    int t = threadIdx.x;
    int w = t >> 6;
    int s = c * 256 + t;
    __shared__ float kT[64][64];
    __shared__ float vT[64][64];
    __shared__ float kG[8][64];
    __shared__ float vG[8][64];

    {   // stage global CLS keys/values (regular k/v projections at GPOS)
        int u = t & 127;
        int g = u >> 4, d = (u & 15) * 4;
        const float* src = qkvg + (size_t)(g * 512) * QKVG_N + (t < 128 ? 768 : 1536) + hh * 64 + d;
        float* dst = (t < 128) ? &kG[g][d] : &vG[g][d];
        *(floatx4*)dst = *(const floatx4*)src;
    }
    floatx4 q4[16];
    {
        const floatx4* qs = (const floatx4*)(qkvg + (size_t)s * QKVG_N + hh * 64);
        #pragma unroll
        for (int r = 0; r < 16; r++) q4[r] = qs[r] * 0.125f;   // fold 1/sqrt(D)
    }
    floatx4 acc4[16];
    #pragma unroll
    for (int r = 0; r < 16; r++) acc4[r] = (floatx4){0.f, 0.f, 0.f, 0.f};
    float m = -1e30f, l = 0.f;
    __syncthreads();

    // ---- global keys (always unmasked) ----
    #pragma unroll 1
    for (int u = 0; u < 8; ++u) {
        const floatx4* kr = (const floatx4*)kG[u];
        floatx4 s4 = (floatx4){0.f, 0.f, 0.f, 0.f};
        #pragma unroll
        for (int r = 0; r < 16; r++) s4 += q4[r] * kr[r];
        float sc = s4.x + s4.y + s4.z + s4.w;
        if (sc > m) {
            float rr = __expf(m - sc); m = sc; l *= rr;
            #pragma unroll
            for (int r = 0; r < 16; r++) acc4[r] *= rr;
        }
        float p = __expf(sc - m);
        l += p;
        const floatx4* vr = (const floatx4*)vG[u];
        #pragma unroll
        for (int r = 0; r < 16; r++) acc4[r] += p * vr[r];
    }

    // ---- banded local window: 12 tiles of 64 keys ----
    int cbase = c * 256 - 256;
    int row = t >> 2, qtr = (t & 3) * 16;
    for (int tt = 0; tt < 12; ++tt) {
        int kp0 = cbase + tt * 64;
        if (kp0 < 0 || kp0 >= S_LEN) continue;   // block-uniform skip
        __syncthreads();                          // prev tile fully consumed
        const float* ks = qkvg + (size_t)(kp0 + row) * QKVG_N + 768 + hh * 64 + qtr;
        const float* vs = qkvg + (size_t)(kp0 + row) * QKVG_N + 1536 + hh * 64 + qtr;
        #pragma unroll
        for (int r = 0; r < 4; r++) {
            *(floatx4*)&kT[row][qtr + r * 4] = *(const floatx4*)(ks + r * 4);
            *(floatx4*)&vT[row][qtr + r * 4] = *(const floatx4*)(vs + r * 4);
        }
        __syncthreads();
        if (tt < w || tt > w + 8) continue;       // wave-level band skip (post-barriers)
        int jb = tt * 64;
        #pragma unroll 1
        for (int u = 0; u < 64; ++u) {
            int jj = jb + u;
            if (jj < t || jj > t + 512) continue; // band mask
            const floatx4* kr = (const floatx4*)kT[u];
            floatx4 s4 = (floatx4){0.f, 0.f, 0.f, 0.f};
            #pragma unroll
            for (int r = 0; r < 16; r++) s4 += q4[r] * kr[r];
            float sc = s4.x + s4.y + s4.z + s4.w;
            if (sc > m) {
                float rr = __expf(m - sc); m = sc; l *= rr;
                #pragma unroll
                for (int r = 0; r < 16; r++) acc4[r] *= rr;
            }
            float p = __expf(sc - m);
            l += p;
            const floatx4* vr = (const floatx4*)vT[u];
            #pragma unroll
            for (int r = 0; r < 16; r++) acc4[r] += p * vr[r];
        }
    }

    float invl = 1.f / l;
    u16* dst = aob + (size_t)s * 768 + hh * 64;
    #pragma unroll
    for (int r = 0; r < 16; r++) {
        floatx4 o = acc4[r] * invl;
        dst[r * 4 + 0] = f2bf(o.x); dst[r * 4 + 1] = f2bf(o.y);
        dst[r * 4 + 2] = f2bf(o.z); dst[r * 4 + 3] = f2bf(o.w);
    }
}

// qg = (h[GPOS] @ Wqg + bqg) * SCALE   -> [8][768] fp32
__global__ __launch_bounds__(256) void qg_proj_k(
    const float* __restrict__ hf, const float* __restrict__ Wqg,
    const float* __restrict__ bqg, float* __restrict__ qgf)
{
    int g = blockIdx.x;
    int col = blockIdx.y * 256 + threadIdx.x;
    __shared__ float hsh[768];
    for (int i = threadIdx.x; i < 768; i += 256) hsh[i] = hf[(size_t)(g * 512) * 768 + i];
    __syncthreads();
    float a = 0.f;
    #pragma unroll 4
    for (int k = 0; k < 768; k++) a += hsh[k] * Wqg[(size_t)k * 768 + col];
    qgf[g * 768 + col] = (a + bqg[col]) * 0.125f;
}

// Global-token full attention over kg/vg (cols 2304/3072 of qkvg), overwrite
// the 8 CLS rows of the attention output.
__global__ __launch_bounds__(256) void attn_global_k(
    const float* __restrict__ qgf, const float* __restrict__ qkvg, u16* __restrict__ aob)
{
    int hh = blockIdx.x, g = blockIdx.y;
    int t = threadIdx.x, lane = t & 63, w = t >> 6;
    __shared__ float qs[64];
    __shared__ float sc[4096];
    __shared__ float rbuf[4];
    __shared__ float oacc[4][64];
    if (t < 64) qs[t] = qgf[g * 768 + hh * 64 + t];
    __syncthreads();
    const floatx4* q4 = (const floatx4*)qs;
    float mymax = -1e30f;
    for (int it = 0; it < 16; ++it) {
        int s = it * 256 + t;
        const floatx4* kr = (const floatx4*)(qkvg + (size_t)s * QKVG_N + 2304 + hh * 64);
        floatx4 a = (floatx4){0.f, 0.f, 0.f, 0.f};
        #pragma unroll
        for (int r = 0; r < 16; r++) a += q4[r] * kr[r];
        float v = a.x + a.y + a.z + a.w;
        sc[s] = v;
        mymax = fmaxf(mymax, v);
    }
    for (int o = 32; o > 0; o >>= 1) mymax = fmaxf(mymax, __shfl_down(mymax, o));
    if (lane == 0) rbuf[w] = mymax;
    __syncthreads();
    float M = fmaxf(fmaxf(rbuf[0], rbuf[1]), fmaxf(rbuf[2], rbuf[3]));
    __syncthreads();
    float mysum = 0.f;
    for (int it = 0; it < 16; ++it) {
        int s = it * 256 + t;
        float p = __expf(sc[s] - M);
        sc[s] = p; mysum += p;
    }
    for (int o = 32; o > 0; o >>= 1) mysum += __shfl_down(mysum, o);
    if (lane == 0) rbuf[w] = mysum;
    __syncthreads();
    float L = rbuf[0] + rbuf[1] + rbuf[2] + rbuf[3];
    float acc = 0.f;
    for (int s = w; s < 4096; s += 4)
        acc += sc[s] * qkvg[(size_t)s * QKVG_N + 3072 + hh * 64 + lane];
    oacc[w][lane] = acc;
    __syncthreads();
    if (t < 64) {
        float o = (oacc[0][t] + oacc[1][t] + oacc[2][t] + oacc[3][t]) / L;
        aob[(size_t)(g * 512) * 768 + hh * 64 + t] = f2bf(o);
    }
}

// Final head: out[g][n] = h[GPOS[g]] . Wout[:,n] + bout[n]   (8 x 128)
__global__ __launch_bounds__(128) void head_k(
    const float* __restrict__ hf, const float* __restrict__ Wout,
    const float* __restrict__ bout, float* __restrict__ out)
{
    int g = blockIdx.x, n = threadIdx.x;
    __shared__ float hsh[768];
    for (int i = n; i < 768; i += 128) hsh[i] = hf[(size_t)(g * 512) * 768 + i];
    __syncthreads();
    float a = 0.f;
    #pragma unroll 4
    for (int k = 0; k < 768; k++) a += hsh[k] * Wout[k * 128 + n];
    out[g * 128 + n] = a + bout[n];
}

// ---------------------------------------------------------------------------
extern "C" void kernel_launch(void* const* d_in, const int* in_sizes, int n_in,
                              void* d_out, int out_size, void* d_ws, size_t ws_size,
                              hipStream_t stream)
{
    (void)in_sizes; (void)n_in; (void)out_size; (void)ws_size;
    const int*   x    = (const int*)  d_in[0];
    const float* wemb = (const float*)d_in[1];
    const float* pemb = (const float*)d_in[2];
    const float* elns = (const float*)d_in[3];
    const float* elnb = (const float*)d_in[4];
    const float* Wq   = (const float*)d_in[5];
    const float* bq   = (const float*)d_in[6];
    const float* Wk   = (const float*)d_in[7];
    const float* bk   = (const float*)d_in[8];
    const float* Wv   = (const float*)d_in[9];
    const float* bv   = (const float*)d_in[10];
    const float* Wo   = (const float*)d_in[11];
    const float* bo   = (const float*)d_in[12];
    const float* Wqg  = (const float*)d_in[13];
    const float* bqg  = (const float*)d_in[14];
    const float* Wkg  = (const float*)d_in[15];
    const float* bkg  = (const float*)d_in[16];
    const float* Wvg  = (const float*)d_in[17];
    const float* bvg  = (const float*)d_in[18];
    const float* l1s  = (const float*)d_in[19];
    const float* l1b  = (const float*)d_in[20];
    const float* W1   = (const float*)d_in[21];
    const float* b1   = (const float*)d_in[22];
    const float* W2   = (const float*)d_in[23];
    const float* b2   = (const float*)d_in[24];
    const float* l2s  = (const float*)d_in[25];
    const float* l2b  = (const float*)d_in[26];
    const float* Wout = (const float*)d_in[27];
    const float* boutp= (const float*)d_in[28];

    char* W = (char*)d_ws;
    float* hf    = (float*)(W);                  // [4096][768]  fp32
    u16*   hb    = (u16*)  (W + 12582912);       // [4096][768]  bf16
    float* qkvg  = (float*)(W + 18874368);       // [4096][3840] fp32
    u16*   aob   = (u16*)  (W + 81788928);       // [4096][768]  bf16
    float* yf    = (float*)(W + 88080384);       // [4096][768]  fp32
    u16*   ff1b  = (u16*)  (W + 100663296);      // [4096][3072] bf16
    float* ff2f  = (float*)(W + 125829120);      // [4096][768]  fp32
    float* qgf   = (float*)(W + 138412032);      // [8][768]     fp32
    float* bcat  = (float*)(W + 138436608);      // [3840]       fp32
    u16*   wT    = (u16*)  (W + 138451968);      // bf16 transposed weights
    u16* wqkvgT = wT;                            // [3840][768]
    u16* woT    = wT + 2949120;                  // [768][768]
    u16* w1T    = wT + 3538944;                  // [3072][768]
    u16* w2T    = wT + 5898240;                  // [768][3072]

    embed_ln_k<<<4096, 256, 0, stream>>>(x, wemb, pemb, elns, elnb, hf, hb);

    for (int l = 0; l < NL; ++l) {
        const float* Wq_l  = Wq  + (size_t)l * 768 * 768;
        const float* Wk_l  = Wk  + (size_t)l * 768 * 768;
        const float* Wv_l  = Wv  + (size_t)l * 768 * 768;
        const float* Wo_l  = Wo  + (size_t)l * 768 * 768;
        const float* Wqg_l = Wqg + (size_t)l * 768 * 768;
        const float* Wkg_l = Wkg + (size_t)l * 768 * 768;
        const float* Wvg_l = Wvg + (size_t)l * 768 * 768;
        const float* W1_l  = W1  + (size_t)l * 768 * 3072;
        const float* W2_l  = W2  + (size_t)l * 3072 * 768;
        const float* bq_l  = bq  + (size_t)l * 768;
        const float* bk_l  = bk  + (size_t)l * 768;
        const float* bv_l  = bv  + (size_t)l * 768;
        const float* bo_l  = bo  + (size_t)l * 768;
        const float* bqg_l = bqg + (size_t)l * 768;
        const float* bkg_l = bkg + (size_t)l * 768;
        const float* bvg_l = bvg + (size_t)l * 768;
        const float* b1_l  = b1  + (size_t)l * 3072;
        const float* b2_l  = b2  + (size_t)l * 768;
        const float* l1s_l = l1s + (size_t)l * 768;
        const float* l1b_l = l1b + (size_t)l * 768;
        const float* l2s_l = l2s + (size_t)l * 768;
        const float* l2b_l = l2b + (size_t)l * 768;

        prep_weights_k<<<8079, 256, 0, stream>>>(
            Wq_l, Wk_l, Wv_l, Wkg_l, Wvg_l, Wo_l, W1_l, W2_l,
            bq_l, bk_l, bv_l, bkg_l, bvg_l,
            wqkvgT, woT, w1T, w2T, bcat);

        // fused q/k/v/kg/vg projection: [4096][768] @ -> [4096][3840]
        gemm_k<0, 1, 0><<<dim3(32, 30), 256, 0, stream>>>(
            hb, wqkvgT, bcat, qkvg, (u16*)nullptr, QKVG_N, 768);

        attn_local_k<<<dim3(12, 16), 256, 0, stream>>>(qkvg, aob);

        qg_proj_k<<<dim3(8, 3), 256, 0, stream>>>(hf, Wqg_l, bqg_l, qgf);
        attn_global_k<<<dim3(12, 8), 256, 0, stream>>>(qgf, qkvg, aob);

        // output projection
        gemm_k<0, 1, 0><<<dim3(32, 6), 256, 0, stream>>>(
            aob, woT, bo_l, yf, (u16*)nullptr, 768, 768);
        ln_resid_k<<<4096, 256, 0, stream>>>(hf, yf, l1s_l, l1b_l, hf, hb);

        // FFN
        gemm_k<1, 0, 1><<<dim3(32, 24), 256, 0, stream>>>(
            hb, w1T, b1_l, (float*)nullptr, ff1b, 3072, 768);
        gemm_k<0, 1, 0><<<dim3(32, 6), 256, 0, stream>>>(
            ff1b, w2T, b2_l, ff2f, (u16*)nullptr, 768, 3072);
        ln_resid_k<<<4096, 256, 0, stream>>>(hf, ff2f, l2s_l, l2b_l, hf, hb);
    }

    head_k<<<8, 128, 0, stream>>>(hf, Wout, boutp, (float*)d_out);
}

// Round 2
// 6129.128 us; speedup vs baseline: 2.0187x; 2.0187x over previous
//
#include <hip/hip_runtime.h>
#include <hip/hip_bf16.h>

// ---------------------------------------------------------------------------
// Longformer forward, MI355X. Round 1: MFMA local attention + bf16 qkvg +
// global_load_lds GEMM staging.
// Constants: B=1 NW=8 SEG=511 S=4096 W=256 C=16 H=12 D=64 DM=768 FF=3072 L=12
// ---------------------------------------------------------------------------

typedef unsigned short u16;
typedef __attribute__((ext_vector_type(4))) float floatx4;
typedef __attribute__((ext_vector_type(4))) unsigned int uintx4;
typedef __attribute__((ext_vector_type(8))) short bf16x8;
typedef __attribute__((ext_vector_type(4))) u16 u16x4;

#define S_LEN 4096
#define QKVG_N 3840   // q(768) k(768) v(768) kg(768) vg(768)
#define NL 12

__device__ inline u16 f2bf(float x) {
    union { __hip_bfloat16 b; u16 u; } cv;
    cv.b = __float2bfloat16(x);
    return cv.u;
}
__device__ inline float bf2f(u16 u) {
    union { float f; unsigned int i; } c; c.i = ((unsigned int)u) << 16; return c.f;
}
__device__ inline float bflo(unsigned int u) {
    union { float f; unsigned int i; } c; c.i = u << 16; return c.f;
}
__device__ inline float bfhi(unsigned int u) {
    union { float f; unsigned int i; } c; c.i = u & 0xffff0000u; return c.f;
}
__device__ inline float gelu_f(float x) {
    float x3 = x * x * x;
    return 0.5f * x * (1.0f + tanhf(0.7978845608028654f * (x + 0.044715f * x3)));
}

#define GLDS16(g, l)                                                              \
    __builtin_amdgcn_global_load_lds(                                             \
        (const __attribute__((address_space(1))) unsigned int*)(g),               \
        (__attribute__((address_space(3))) unsigned int*)(l), 16, 0, 0)

// ---------------------------------------------------------------------------
// Weight prep: fp32 [K][N] -> bf16 [N][K] (transposed) + bias concat.
// ---------------------------------------------------------------------------
__global__ __launch_bounds__(256) void prep_weights_k(
    const float* __restrict__ Wq, const float* __restrict__ Wk, const float* __restrict__ Wv,
    const float* __restrict__ Wkg, const float* __restrict__ Wvg, const float* __restrict__ Wo,
    const float* __restrict__ W1, const float* __restrict__ W2,
    const float* __restrict__ bq, const float* __restrict__ bk, const float* __restrict__ bv,
    const float* __restrict__ bkg, const float* __restrict__ bvg,
    u16* __restrict__ wqkvgT, u16* __restrict__ woT, u16* __restrict__ w1T,
    u16* __restrict__ w2T, float* __restrict__ bcat)
{
    int bid = blockIdx.x;
    int t = threadIdx.x;
    if (bid >= 8064) {                       // bias concat tail: 3840 floats
        int i = (bid - 8064) * 256 + t;
        float v;
        if (i < 768)       v = bq[i];
        else if (i < 1536) v = bk[i - 768];
        else if (i < 2304) v = bv[i - 1536];
        else if (i < 3072) v = bkg[i - 2304];
        else               v = bvg[i - 3072];
        bcat[i] = v;
        return;
    }
    const float* src; u16* dst; int K, N, tile;
    if (bid < 2880) {
        int m = bid / 576; tile = bid % 576;
        src = (m == 0) ? Wq : (m == 1) ? Wk : (m == 2) ? Wv : (m == 3) ? Wkg : Wvg;
        dst = wqkvgT + (size_t)m * 589824;   // 768*768
        K = 768; N = 768;
    } else if (bid < 3456) { tile = bid - 2880; src = Wo; dst = woT; K = 768; N = 768; }
    else if (bid < 5760)   { tile = bid - 3456; src = W1; dst = w1T; K = 768; N = 3072; }
    else                   { tile = bid - 5760; src = W2; dst = w2T; K = 3072; N = 768; }

    int nt = N >> 5;
    int k0 = (tile / nt) << 5, n0 = (tile % nt) << 5;
    __shared__ float tb[32][33];
    int tx = t & 31, ty = t >> 5;            // ty: 0..7
    #pragma unroll
    for (int r = 0; r < 4; r++)
        tb[ty + r * 8][tx] = src[(size_t)(k0 + ty + r * 8) * N + n0 + tx];
    __syncthreads();
    #pragma unroll
    for (int r = 0; r < 4; r++) {
        int nn = ty + r * 8;
        dst[(size_t)(n0 + nn) * K + k0 + tx] = f2bf(tb[tx][nn]);
    }
}

// ---------------------------------------------------------------------------
// bf16 MFMA GEMM with global_load_lds staging (m97 pattern).
// ---------------------------------------------------------------------------
template <int ACT, int WF, int WB>
__global__ __launch_bounds__(256) void gemm_k(
    const u16* __restrict__ A, const u16* __restrict__ Bt,
    const float* __restrict__ bias,
    float* __restrict__ Cf, u16* __restrict__ Cb,
    int N, int K)
{
    __shared__ __align__(16) u16 As[128][32];
    __shared__ __align__(16) u16 Bs[128][32];
    int bm = blockIdx.x * 128, bn = blockIdx.y * 128;
    int t = threadIdx.x, lane = t & 63, wv = t >> 6;
    int wm = (wv >> 1) * 64, wn = (wv & 1) * 64;
    int arow = t >> 2, acol = (t & 3) * 8;     // staging: 64 rows x (4x8 bf16)
    int fr = lane & 15, fo = (lane >> 4) * 8;  // fragment row / k-offset

    floatx4 acc[4][4];
    #pragma unroll
    for (int i = 0; i < 4; i++)
        #pragma unroll
        for (int j = 0; j < 4; j++) acc[i][j] = (floatx4){0.f, 0.f, 0.f, 0.f};

    const int nk = K >> 5;
    for (int kt = 0; kt < nk; ++kt) {
        const u16* ag = A  + (size_t)(bm + arow) * K + kt * 32 + acol;
        const u16* bg = Bt + (size_t)(bn + arow) * K + kt * 32 + acol;
        GLDS16(ag,                   &As[arow][acol]);
        GLDS16(ag + (size_t)64 * K,  &As[arow + 64][acol]);
        GLDS16(bg,                   &Bs[arow][acol]);
        GLDS16(bg + (size_t)64 * K,  &Bs[arow + 64][acol]);
        __syncthreads();
        bf16x8 af[4], bfr[4];
        #pragma unroll
        for (int i = 0; i < 4; i++) af[i]  = *(const bf16x8*)&As[wm + i * 16 + fr][fo];
        #pragma unroll
        for (int i = 0; i < 4; i++) bfr[i] = *(const bf16x8*)&Bs[wn + i * 16 + fr][fo];
        #pragma unroll
        for (int i = 0; i < 4; i++)
            #pragma unroll
            for (int j = 0; j < 4; j++)
                acc[i][j] = __builtin_amdgcn_mfma_f32_16x16x32_bf16(af[i], bfr[j], acc[i][j], 0, 0, 0);
        __syncthreads();
    }

    int dr = (lane >> 4) * 4, dc = lane & 15;
    #pragma unroll
    for (int i = 0; i < 4; i++) {
        #pragma unroll
        for (int j = 0; j < 4; j++) {
            int r0 = bm + wm + i * 16 + dr;
            int cc = bn + wn + j * 16 + dc;
            float bsv = bias[cc];
            #pragma unroll
            for (int r = 0; r < 4; r++) {
                float v = acc[i][j][r] + bsv;
                if (ACT == 1) v = gelu_f(v);
                if (WF) Cf[(size_t)(r0 + r) * N + cc] = v;
                if (WB) Cb[(size_t)(r0 + r) * N + cc] = f2bf(v);
            }
        }
    }
}

// ---------------------------------------------------------------------------
// V transpose per layer: qkvg[s][1536+c] -> vTg[c][s]  (c in [0,768))
// ---------------------------------------------------------------------------
__global__ __launch_bounds__(256) void vtrans_k(
    const u16* __restrict__ qkvg, u16* __restrict__ vTg)
{
    int sb = blockIdx.x * 64, cb = blockIdx.y * 64;
    int t = threadIdx.x;
    __shared__ __align__(16) u16 lt[64][72];
    for (int c = t; c < 512; c += 256) {
        int sr = c >> 3, c0 = (c & 7) * 8;
        uintx4 d4 = *(const uintx4*)(qkvg + (size_t)(sb + sr) * QKVG_N + 1536 + cb + c0);
        const u16* u = (const u16*)&d4;
        #pragma unroll
        for (int j = 0; j < 8; ++j) lt[c0 + j][sr] = u[j];
    }
    __syncthreads();
    for (int c = t; c < 512; c += 256) {
        int cr = c >> 3, s0 = (c & 7) * 8;
        *(uintx4*)(vTg + (size_t)(cb + cr) * 4096 + sb + s0) = *(const uintx4*)&lt[cr][s0];
    }
}

// ---------------------------------------------------------------------------
// MFMA local banded attention + joint softmax with 8 global CLS keys.
// Block: (head, 64-query tile); 4 waves x 16 queries. Computes S^T via
// mfma(A=K, B=Q) so softmax state is per-lane-column; P round-trips through
// wave-private LDS into A-layout; PV uses pre-transposed V (vTg).
// Tile 0 = the 8 global CLS keys; tiles 1..9 = 64-key local band tiles.
// ---------------------------------------------------------------------------
__global__ __launch_bounds__(256) void attn_local_k(
    const u16* __restrict__ qkvg, const u16* __restrict__ vTg, u16* __restrict__ aob)
{
    const int hh = blockIdx.x, qb = blockIdx.y;
    const int t = threadIdx.x, lane = t & 63, w = t >> 6;
    const int g = lane >> 4, qi = lane & 15;
    __shared__ __align__(16) u16 ks[64][72];
    __shared__ __align__(16) u16 vt[64][72];
    __shared__ __align__(16) u16 pbuf[4][16][40];

    const int q0w = qb * 64 + w * 16;
    const int sq = q0w + qi;                 // softmax-column query (per lane)

    bf16x8 qf0, qf1;                          // Q B-operand frags (2 k-steps)
    {
        const u16* qp = qkvg + (size_t)(q0w + qi) * QKVG_N + hh * 64 + g * 8;
        qf0 = *(const bf16x8*)qp;
        qf1 = *(const bf16x8*)(qp + 32);
    }

    floatx4 acc[4];
    #pragma unroll
    for (int i = 0; i < 4; i++) acc[i] = (floatx4){0.f, 0.f, 0.f, 0.f};
    float mrun = -1e30f, lrun = 0.f;

    for (int tile = 0; tile <= 9; ++tile) {
        const int kbase = qb * 64 - 256 + (tile - 1) * 64;
        if (tile > 0 && (kbase < -63 || kbase >= S_LEN)) continue;  // uniform skip
        __syncthreads();
        if (tile == 0) {
            // zero vt (avoid NaN junk x P=0), then fill 8 global K/V columns
            for (int i = t; i < 576; i += 256) ((uintx4*)vt)[i] = (uintx4){0, 0, 0, 0};
            __syncthreads();
            if (t < 64) {
                int gg = t >> 3, d0 = (t & 7) * 8;
                *(uintx4*)&ks[gg][d0] =
                    *(const uintx4*)(qkvg + (size_t)(gg * 512) * QKVG_N + 768 + hh * 64 + d0);
            }
            for (int e = t; e < 512; e += 256) {
                int d = e >> 3, gg = e & 7;
                vt[d][gg] = vTg[(size_t)(hh * 64 + d) * 4096 + gg * 512];
            }
        } else {
            for (int c = t; c < 512; c += 256) {
                int r = c >> 3, c0 = (c & 7) * 8;
                int row = kbase + r; row = row < 0 ? 0 : (row > 4095 ? 4095 : row);
                *(uintx4*)&ks[r][c0] =
                    *(const uintx4*)(qkvg + (size_t)row * QKVG_N + 768 + hh * 64 + c0);
                int gc = kbase + c0; gc = gc < 0 ? 0 : (gc > 4088 ? 4088 : gc);
                *(uintx4*)&vt[r][c0] =
                    *(const uintx4*)(vTg + (size_t)(hh * 64 + r) * 4096 + gc);
            }
        }
        __syncthreads();

        const bool gt = (tile == 0);
        const int ng = gt ? 1 : 2;
        for (int kg2 = 0; kg2 < ng; ++kg2) {
            floatx4 sf[2];
            sf[1] = (floatx4){0.f, 0.f, 0.f, 0.f};
            {
                bf16x8 ka0 = *(const bf16x8*)&ks[kg2 * 32 + qi][g * 8];
                bf16x8 ka1 = *(const bf16x8*)&ks[kg2 * 32 + qi][32 + g * 8];
                floatx4 z = (floatx4){0.f, 0.f, 0.f, 0.f};
                z = __builtin_amdgcn_mfma_f32_16x16x32_bf16(ka0, qf0, z, 0, 0, 0);
                sf[0] = __builtin_amdgcn_mfma_f32_16x16x32_bf16(ka1, qf1, z, 0, 0, 0);
            }
            if (!gt) {
                bf16x8 kb0 = *(const bf16x8*)&ks[kg2 * 32 + 16 + qi][g * 8];
                bf16x8 kb1 = *(const bf16x8*)&ks[kg2 * 32 + 16 + qi][32 + g * 8];
                floatx4 z = (floatx4){0.f, 0.f, 0.f, 0.f};
                z = __builtin_amdgcn_mfma_f32_16x16x32_bf16(kb0, qf0, z, 0, 0, 0);
                sf[1] = __builtin_amdgcn_mfma_f32_16x16x32_bf16(kb1, qf1, z, 0, 0, 0);
            }
            // scores: lane holds keys kl = kg2*32 + f*16 + g*4 + r for query sq
            float p8[8];
            float mloc = -1e30f;
            #pragma unroll
            for (int f = 0; f < 2; ++f)
                #pragma unroll
                for (int r = 0; r < 4; ++r) {
                    int kl = kg2 * 32 + f * 16 + g * 4 + r;
                    bool valid;
                    if (gt) valid = (kl < 8);
                    else {
                        int kp = kbase + kl, dd = kp - sq;
                        valid = (kp >= 0) & (kp < S_LEN) & (dd <= 256) & (dd >= -256);
                    }
                    float sc = valid ? sf[f][r] * 0.125f : -1e30f;
                    p8[f * 4 + r] = sc;
                    mloc = fmaxf(mloc, sc);
                }
            mloc = fmaxf(mloc, __shfl_xor(mloc, 16));
            mloc = fmaxf(mloc, __shfl_xor(mloc, 32));
            float mnew = fmaxf(mrun, mloc);
            float alpha = __expf(mrun - mnew);
            mrun = mnew;
            float ls = 0.f;
            #pragma unroll
            for (int i = 0; i < 8; ++i) { float p = __expf(p8[i] - mnew); p8[i] = p; ls += p; }
            ls += __shfl_xor(ls, 16);
            ls += __shfl_xor(ls, 32);
            lrun = lrun * alpha + ls;
            // pack P -> wave-private LDS (row q=qi, cols f*16 + g*4 ..+3)
            u16x4 w0, w1;
            #pragma unroll
            for (int r = 0; r < 4; ++r) { w0[r] = f2bf(p8[r]); w1[r] = f2bf(p8[4 + r]); }
            *(u16x4*)&pbuf[w][qi][g * 4] = w0;
            *(u16x4*)&pbuf[w][qi][16 + g * 4] = w1;
            // rescale acc rows (row m = g*4+r, alpha lives at lane m)
            float al[4];
            #pragma unroll
            for (int r = 0; r < 4; ++r) al[r] = __shfl(alpha, g * 4 + r);
            #pragma unroll
            for (int dt = 0; dt < 4; ++dt)
                #pragma unroll
                for (int r = 0; r < 4; ++r) acc[dt][r] *= al[r];
            // P A-frag + PV MFMAs
            bf16x8 pf = *(const bf16x8*)&pbuf[w][qi][g * 8];
            #pragma unroll
            for (int dt = 0; dt < 4; ++dt) {
                bf16x8 vb = *(const bf16x8*)&vt[dt * 16 + qi][kg2 * 32 + g * 8];
                acc[dt] = __builtin_amdgcn_mfma_f32_16x16x32_bf16(pf, vb, acc[dt], 0, 0, 0);
            }
        }
    }

    float inv = 1.f / lrun;
    float li[4];
    #pragma unroll
    for (int r = 0; r < 4; ++r) li[r] = __shfl(inv, g * 4 + r);
    #pragma unroll
    for (int dt = 0; dt < 4; ++dt)
        #pragma unroll
        for (int r = 0; r < 4; ++r) {
            int s = q0w + g * 4 + r;
            aob[(size_t)s * 768 + hh * 64 + dt * 16 + qi] = f2bf(acc[dt][r] * li[r]);
        }
}

// ---------------------------------------------------------------------------
// LayerNorm helpers
// ---------------------------------------------------------------------------
#define BLOCK_MEANVAR(sum, sq, mean, inv)                                        \
    {                                                                            \
        for (int o_ = 32; o_ > 0; o_ >>= 1) {                                    \
            sum += __shfl_down(sum, o_); sq += __shfl_down(sq, o_);              \
        }                                                                        \
        __shared__ float rs_[4], rq_[4];                                         \
        if ((threadIdx.x & 63) == 0) { rs_[threadIdx.x >> 6] = sum; rq_[threadIdx.x >> 6] = sq; } \
        __syncthreads();                                                         \
        float S_ = rs_[0] + rs_[1] + rs_[2] + rs_[3];                            \
        float Q_ = rq_[0] + rq_[1] + rq_[2] + rq_[3];                            \
        mean = S_ * (1.f / 768.f);                                               \
        float var_ = Q_ * (1.f / 768.f) - mean * mean;                           \
        inv = rsqrtf(var_ + 1e-5f);                                              \
    }

__global__ __launch_bounds__(256) void embed_ln_k(
    const int* __restrict__ x, const float* __restrict__ wemb, const float* __restrict__ pemb,
    const float* __restrict__ gs, const float* __restrict__ gb,
    float* __restrict__ hf, u16* __restrict__ hb)
{
    int s = blockIdx.x, t = threadIdx.x;
    int w = s >> 9, p = s & 511;
    int id = (p == 0) ? 0 : x[w * 511 + p - 1];
    float v[3], sum = 0.f, sq = 0.f;
    #pragma unroll
    for (int r = 0; r < 3; r++) {
        int d = t + r * 256;
        float e = wemb[(size_t)id * 768 + d] + pemb[(size_t)s * 768 + d];
        v[r] = e; sum += e; sq += e * e;
    }
    float mean, inv;
    BLOCK_MEANVAR(sum, sq, mean, inv)
    #pragma unroll
    for (int r = 0; r < 3; r++) {
        int d = t + r * 256;
        float y = (v[r] - mean) * inv * gs[d] + gb[d];
        hf[(size_t)s * 768 + d] = y;
        hb[(size_t)s * 768 + d] = f2bf(y);
    }
}

__global__ __launch_bounds__(256) void ln_resid_k(
    const float* __restrict__ xa, const float* __restrict__ xb,
    const float* __restrict__ gs, const float* __restrict__ gb,
    float* __restrict__ of, u16* __restrict__ ob)
{
    int s = blockIdx.x, t = threadIdx.x;
    const float* pa = xa + (size_t)s * 768;
    const float* pb = xb + (size_t)s * 768;
    float v[3], sum = 0.f, sq = 0.f;
    #pragma unroll
    for (int r = 0; r < 3; r++) {
        int d = t + r * 256;
        float e = pa[d] + pb[d];
        v[r] = e; sum += e; sq += e * e;
    }
    float mean, inv;
    BLOCK_MEANVAR(sum, sq, mean, inv)
    #pragma unroll
    for (int r = 0; r < 3; r++) {
        int d = t + r * 256;
        float y = (v[r] - mean) * inv * gs[d] + gb[d];
        of[(size_t)s * 768 + d] = y;
        ob[(size_t)s * 768 + d] = f2bf(y);
    }
}

// qg = (h[GPOS] @ Wqg + bqg) * SCALE   -> [8][768] fp32
__global__ __launch_bounds__(256) void qg_proj_k(
    const float* __restrict__ hf, const float* __restrict__ Wqg,
    const float* __restrict__ bqg, float* __restrict__ qgf)
{
    int g = blockIdx.x;
    int col = blockIdx.y * 256 + threadIdx.x;
    __shared__ float hsh[768];
    for (int i = threadIdx.x; i < 768; i += 256) hsh[i] = hf[(size_t)(g * 512) * 768 + i];
    __syncthreads();
    float a = 0.f;
    #pragma unroll 4
    for (int k = 0; k < 768; k++) a += hsh[k] * Wqg[(size_t)k * 768 + col];
    qgf[g * 768 + col] = (a + bqg[col]) * 0.125f;
}

// Global-token full attention over kg/vg (bf16 qkvg cols 2304/3072).
__global__ __launch_bounds__(512) void attn_global_k(
    const float* __restrict__ qgf, const u16* __restrict__ qkvg, u16* __restrict__ aob)
{
    int hh = blockIdx.x, gq = blockIdx.y;
    int t = threadIdx.x, lane = t & 63, w = t >> 6;
    __shared__ float qs[64];
    __shared__ float sc[4096];
    __shared__ float rbuf[8];
    __shared__ float oacc[8][64];
    if (t < 64) qs[t] = qgf[gq * 768 + hh * 64 + t];
    __syncthreads();
    float mymax = -1e30f;
    for (int it = 0; it < 8; ++it) {
        int s = it * 512 + t;
        const uintx4* kr = (const uintx4*)(qkvg + (size_t)s * QKVG_N + 2304 + hh * 64);
        float a = 0.f;
        #pragma unroll
        for (int ch = 0; ch < 8; ++ch) {
            uintx4 pk = kr[ch];
            #pragma unroll
            for (int e = 0; e < 4; ++e)
                a += bflo(pk[e]) * qs[ch * 8 + 2 * e] + bfhi(pk[e]) * qs[ch * 8 + 2 * e + 1];
        }
        sc[s] = a; mymax = fmaxf(mymax, a);
    }
    #pragma unroll
    for (int o = 32; o > 0; o >>= 1) mymax = fmaxf(mymax, __shfl_down(mymax, o));
    if (lane == 0) rbuf[w] = mymax;
    __syncthreads();
    float M = -1e30f;
    #pragma unroll
    for (int i = 0; i < 8; ++i) M = fmaxf(M, rbuf[i]);
    __syncthreads();
    float mysum = 0.f;
    for (int it = 0; it < 8; ++it) {
        int s = it * 512 + t;
        float p = __expf(sc[s] - M);
        sc[s] = p; mysum += p;
    }
    #pragma unroll
    for (int o = 32; o > 0; o >>= 1) mysum += __shfl_down(mysum, o);
    if (lane == 0) rbuf[w] = mysum;
    __syncthreads();
    float L = 0.f;
    #pragma unroll
    for (int i = 0; i < 8; ++i) L += rbuf[i];
    float acc = 0.f;
    for (int s = w; s < 4096; s += 8)
        acc += sc[s] * bf2f(qkvg[(size_t)s * QKVG_N + 3072 + hh * 64 + lane]);
    oacc[w][lane] = acc;
    __syncthreads();
    if (t < 64) {
        float o = 0.f;
        #pragma unroll
        for (int i = 0; i < 8; ++i) o += oacc[i][t];
        aob[(size_t)(gq * 512) * 768 + hh * 64 + t] = f2bf(o / L);
    }
}

__global__ __launch_bounds__(128) void head_k(
    const float* __restrict__ hf, const float* __restrict__ Wout,
    const float* __restrict__ bout, float* __restrict__ out)
{
    int g = blockIdx.x, n = threadIdx.x;
    __shared__ float hsh[768];
    for (int i = n; i < 768; i += 128) hsh[i] = hf[(size_t)(g * 512) * 768 + i];
    __syncthreads();
    float a = 0.f;
    #pragma unroll 4
    for (int k = 0; k < 768; k++) a += hsh[k] * Wout[k * 128 + n];
    out[g * 128 + n] = a + bout[n];
}

// ---------------------------------------------------------------------------
extern "C" void kernel_launch(void* const* d_in, const int* in_sizes, int n_in,
                              void* d_out, int out_size, void* d_ws, size_t ws_size,
                              hipStream_t stream)
{
    (void)in_sizes; (void)n_in; (void)out_size; (void)ws_size;
    const int*   x    = (const int*)  d_in[0];
    const float* wemb = (const float*)d_in[1];
    const float* pemb = (const float*)d_in[2];
    const float* elns = (const float*)d_in[3];
    const float* elnb = (const float*)d_in[4];
    const float* Wq   = (const float*)d_in[5];
    const float* bq   = (const float*)d_in[6];
    const float* Wk   = (const float*)d_in[7];
    const float* bk   = (const float*)d_in[8];
    const float* Wv   = (const float*)d_in[9];
    const float* bv   = (const float*)d_in[10];
    const float* Wo   = (const float*)d_in[11];
    const float* bo   = (const float*)d_in[12];
    const float* Wqg  = (const float*)d_in[13];
    const float* bqg  = (const float*)d_in[14];
    const float* Wkg  = (const float*)d_in[15];
    const float* bkg  = (const float*)d_in[16];
    const float* Wvg  = (const float*)d_in[17];
    const float* bvg  = (const float*)d_in[18];
    const float* l1s  = (const float*)d_in[19];
    const float* l1b  = (const float*)d_in[20];
    const float* W1   = (const float*)d_in[21];
    const float* b1   = (const float*)d_in[22];
    const float* W2   = (const float*)d_in[23];
    const float* b2   = (const float*)d_in[24];
    const float* l2s  = (const float*)d_in[25];
    const float* l2b  = (const float*)d_in[26];
    const float* Wout = (const float*)d_in[27];
    const float* boutp= (const float*)d_in[28];

    char* W = (char*)d_ws;
    float* hf    = (float*)(W);                  // [4096][768]  fp32
    u16*   hb    = (u16*)  (W + 12582912);       // [4096][768]  bf16
    u16*   qkvg  = (u16*)  (W + 18874368);       // [4096][3840] bf16
    u16*   vTg   = (u16*)  (W + 50331648);       // [768][4096]  bf16
    u16*   aob   = (u16*)  (W + 56623104);       // [4096][768]  bf16
    float* yf    = (float*)(W + 62914560);       // [4096][768]  fp32
    u16*   ff1b  = (u16*)  (W + 75497472);       // [4096][3072] bf16
    float* ff2f  = (float*)(W + 100663296);      // [4096][768]  fp32
    float* qgf   = (float*)(W + 113246208);      // [8][768]     fp32
    float* bcat  = (float*)(W + 113270784);      // [3840]       fp32
    u16*   wT    = (u16*)  (W + 113286144);      // bf16 transposed weights
    u16* wqkvgT = wT;                            // [3840][768]
    u16* woT    = wT + 2949120;                  // [768][768]
    u16* w1T    = wT + 3538944;                  // [3072][768]
    u16* w2T    = wT + 5898240;                  // [768][3072]

    embed_ln_k<<<4096, 256, 0, stream>>>(x, wemb, pemb, elns, elnb, hf, hb);

    for (int l = 0; l < NL; ++l) {
        const float* Wq_l  = Wq  + (size_t)l * 768 * 768;
        const float* Wk_l  = Wk  + (size_t)l * 768 * 768;
        const float* Wv_l  = Wv  + (size_t)l * 768 * 768;
        const float* Wo_l  = Wo  + (size_t)l * 768 * 768;
        const float* Wqg_l = Wqg + (size_t)l * 768 * 768;
        const float* Wkg_l = Wkg + (size_t)l * 768 * 768;
        const float* Wvg_l = Wvg + (size_t)l * 768 * 768;
        const float* W1_l  = W1  + (size_t)l * 768 * 3072;
        const float* W2_l  = W2  + (size_t)l * 3072 * 768;
        const float* bq_l  = bq  + (size_t)l * 768;
        const float* bk_l  = bk  + (size_t)l * 768;
        const float* bv_l  = bv  + (size_t)l * 768;
        const float* bo_l  = bo  + (size_t)l * 768;
        const float* bqg_l = bqg + (size_t)l * 768;
        const float* bkg_l = bkg + (size_t)l * 768;
        const float* bvg_l = bvg + (size_t)l * 768;
        const float* b1_l  = b1  + (size_t)l * 3072;
        const float* b2_l  = b2  + (size_t)l * 768;
        const float* l1s_l = l1s + (size_t)l * 768;
        const float* l1b_l = l1b + (size_t)l * 768;
        const float* l2s_l = l2s + (size_t)l * 768;
        const float* l2b_l = l2b + (size_t)l * 768;

        prep_weights_k<<<8079, 256, 0, stream>>>(
            Wq_l, Wk_l, Wv_l, Wkg_l, Wvg_l, Wo_l, W1_l, W2_l,
            bq_l, bk_l, bv_l, bkg_l, bvg_l,
            wqkvgT, woT, w1T, w2T, bcat);

        // fused q/k/v/kg/vg projection -> bf16 [4096][3840]
        gemm_k<0, 0, 1><<<dim3(32, 30), 256, 0, stream>>>(
            hb, wqkvgT, bcat, (float*)nullptr, qkvg, QKVG_N, 768);

        vtrans_k<<<dim3(64, 12), 256, 0, stream>>>(qkvg, vTg);

        attn_local_k<<<dim3(12, 64), 256, 0, stream>>>(qkvg, vTg, aob);

        qg_proj_k<<<dim3(8, 3), 256, 0, stream>>>(hf, Wqg_l, bqg_l, qgf);
        attn_global_k<<<dim3(12, 8), 512, 0, stream>>>(qgf, qkvg, aob);

        gemm_k<0, 1, 0><<<dim3(32, 6), 256, 0, stream>>>(
            aob, woT, bo_l, yf, (u16*)nullptr, 768, 768);
        ln_resid_k<<<4096, 256, 0, stream>>>(hf, yf, l1s_l, l1b_l, hf, hb);

        gemm_k<1, 0, 1><<<dim3(32, 24), 256, 0, stream>>>(
            hb, w1T, b1_l, (float*)nullptr, ff1b, 3072, 768);
        gemm_k<0, 1, 0><<<dim3(32, 6), 256, 0, stream>>>(
            ff1b, w2T, b2_l, ff2f, (u16*)nullptr, 768, 3072);
        ln_resid_k<<<4096, 256, 0, stream>>>(hf, ff2f, l2s_l, l2b_l, hf, hb);
    }

    head_k<<<8, 128, 0, stream>>>(hf, Wout, boutp, (float*)d_out);
}